// Round 9
// baseline (1222.747 us; speedup 1.0000x reference)
//
#include <hip/hip_runtime.h>
#include <hip/hip_bf16.h>
#include <stdint.h>

#define T_LEN 8192
#define LAYERS 30

typedef __attribute__((ext_vector_type(8))) short bfx8;
typedef __attribute__((ext_vector_type(4))) float fx4;
typedef __attribute__((ext_vector_type(4))) int ix4;
typedef unsigned long long u64;

static __device__ __forceinline__ unsigned short f2bf(float f) {
    union { float fv; unsigned u; } v; v.fv = f;
    unsigned r = v.u + 0x7fffu + ((v.u >> 16) & 1u);
    return (unsigned short)(r >> 16);
}
static __device__ __forceinline__ unsigned pack2(float a, float b) {
    return (unsigned)f2bf(a) | ((unsigned)f2bf(b) << 16);
}
static __device__ __forceinline__ u64 pack4(float a, float b, float c, float d) {
    return (u64)pack2(a, b) | ((u64)pack2(c, d) << 32);
}
// Agent-scope RELAXED atomics: sc1 data path (bypasses non-coherent per-XCD L2,
// coherent at L3). No acq/rel -> no L2 writeback/invalidate (R3's cost).
static __device__ __forceinline__ u64 aload(const unsigned short* p) {
    return __hip_atomic_load((const u64*)p, __ATOMIC_RELAXED, __HIP_MEMORY_SCOPE_AGENT);
}
static __device__ __forceinline__ void astore(unsigned short* p, u64 v) {
    __hip_atomic_store((u64*)p, v, __ATOMIC_RELAXED, __HIP_MEMORY_SCOPE_AGENT);
}

// ---------------------------------------------------------------------------
// Weight packing (layout validated R0-R6) + zero the barrier counters (8 KB).
// ---------------------------------------------------------------------------
__global__ void pack_weights_k(const float* __restrict__ conv_w,
                               const float* __restrict__ aux_w,
                               const float* __restrict__ out_w,
                               unsigned short* __restrict__ wpack,
                               unsigned* __restrict__ bar) {
    if (blockIdx.x == 0)
        for (int i = threadIdx.x; i < 2048; i += 256) bar[i] = 0u;
    int tid = blockIdx.x * 256 + threadIdx.x;   // total 30*88*64 = 168960
    if (tid >= 168960) return;
    int lane = tid & 63;
    int f = (tid >> 6) % 88;
    int l = tid / (88 * 64);
    unsigned short vals[8];
#pragma unroll
    for (int j = 0; j < 8; j++) {
        int kl = ((lane >> 4) * 8) + j;
        float v;
        if (f < 72) {
            int ks = f >> 3, nf = f & 7;
            int g = nf * 16 + (lane & 15);
            if (ks < 6) {
                int tap = ks >> 1;
                int i = (ks & 1) * 32 + kl;
                v = conv_w[((l * 128 + g) * 64 + i) * 3 + tap];
            } else {
                int a = (ks - 6) * 32 + kl;
                v = (a < 80) ? aux_w[(l * 128 + g) * 80 + a] : 0.f;
            }
        } else {
            int fo = f - 72;
            int ks = fo >> 3, nf = fo & 7;
            int p = nf * 16 + (lane & 15);
            v = out_w[(l * 128 + p) * 64 + ks * 32 + kl];
        }
        vals[j] = f2bf(v);
    }
    unsigned* dst = (unsigned*)(wpack + (size_t)tid * 8);
    dst[0] = (unsigned)vals[0] | ((unsigned)vals[1] << 16);
    dst[1] = (unsigned)vals[2] | ((unsigned)vals[3] << 16);
    dst[2] = (unsigned)vals[4] | ((unsigned)vals[5] << 16);
    dst[3] = (unsigned)vals[6] | ((unsigned)vals[7] << 16);
}

// c (B,80,T) f32 -> cbf (B,T,96) bf16 zero-padded
__global__ void prep_c_k(const float* __restrict__ c, unsigned short* __restrict__ cbf) {
    __shared__ float tile[80][65];
    int bid = blockIdx.x;                 // B * 128 tiles
    int b = bid >> 7;
    int t0 = (bid & 127) << 6;
    for (int idx = threadIdx.x; idx < 80 * 64; idx += 256) {
        int a = idx >> 6, tt = idx & 63;
        tile[a][tt] = c[((size_t)(b * 80 + a)) * T_LEN + t0 + tt];
    }
    __syncthreads();
    for (int idx = threadIdx.x; idx < 64 * 96; idx += 256) {
        int tt = idx / 96, a = idx % 96;
        float v = (a < 80) ? tile[a][tt] : 0.f;
        cbf[((size_t)(b * T_LEN + t0 + tt)) * 96 + a] = f2bf(v);
    }
}

// Relaxed-only grid barrier: 64 leaves (32 u32 apart = 128 B) x 16 arrivals,
// master at bar[2047] (own cacheline). __syncthreads() drains each wave's
// sc1 stores (vmcnt) before the arrive -> data at L3 before anyone proceeds.
static __device__ __forceinline__ void gbar(unsigned* bar, int bid, unsigned target) {
    __syncthreads();
    if (threadIdx.x == 0) {
        unsigned v = __hip_atomic_fetch_add(&bar[(bid & 63) << 5], 1u,
                                            __ATOMIC_RELAXED, __HIP_MEMORY_SCOPE_AGENT);
        if ((v & 15u) == 15u)
            __hip_atomic_fetch_add(&bar[2047], 1u,
                                   __ATOMIC_RELAXED, __HIP_MEMORY_SCOPE_AGENT);
        while (__hip_atomic_load(&bar[2047], __ATOMIC_RELAXED,
                                 __HIP_MEMORY_SCOPE_AGENT) < target)
            __builtin_amdgcn_s_sleep(4);
    }
    __syncthreads();
    __builtin_amdgcn_sched_barrier(0);
}

// ---------------------------------------------------------------------------
// Persistent WaveNet. 1024 blocks = exactly 4/CU x 256 CU (LDS 40960, VGPR<=128
// via launch_bounds) -> all co-resident by capacity; PLAIN launch (no coop API).
// Per-thread state (row tq_t = tid>>2, chunk tq_q = tid&3): xc[16] f32 x-master.
// Waves 2-3 hold skip in f32 MFMA fragments racc[4][2] (R3-proven, no LDS trip).
// LDS: [0,27648) transient: xtap[3][64][72]u16 | sg[64][68]f32 + z[64][72]u16
//      | o_l[64][68]f32 (x-half ONLY, p<64 -> stride 68 safe; R7 bug fixed)
//      [27648,40960) ctile[64][104]u16 persistent, mask f32 in pad @ short 96.
// Cross-block x exchange: bf16 via relaxed agent (sc1) u64 atomics in xbfA/B.
// Weights/cbf/biases: plain cached reads -> L2-hot across all 30 layers.
// ---------------------------------------------------------------------------
__global__ __launch_bounds__(256, 4) void mega_k(
    const float* __restrict__ xin, const float* __restrict__ xmask,
    const unsigned short* __restrict__ cbf,
    const float* __restrict__ fw, const float* __restrict__ fb,
    const float* __restrict__ conv_b, const float* __restrict__ out_b,
    const float* __restrict__ lw1, const float* __restrict__ lb1,
    const float* __restrict__ lw2, const float* __restrict__ lb2,
    unsigned short* __restrict__ xbfA, unsigned short* __restrict__ xbfB,
    const unsigned short* __restrict__ wpack,
    unsigned* __restrict__ bar, float* __restrict__ out)
{
    __shared__ char smem[40960];
    unsigned short* xtap  = (unsigned short*)smem;             // [3][64][72] u16
    float*          sg_l  = (float*)smem;                      // [64][68] f32
    unsigned short* z_l   = (unsigned short*)(smem + 17408);   // [64][72] u16
    float*          o_l   = (float*)smem;                      // [64][68] f32 (x half)
    unsigned short* ctile = (unsigned short*)(smem + 27648);   // [64][104] u16 persistent

    const int tid = threadIdx.x;
    const int lane = tid & 63;
    const int wv = tid >> 6;
    const int bid = (((int)blockIdx.x & 7) * 128) + ((int)blockIdx.x >> 3); // XCD-chunked
    const int b = bid >> 7;
    const int t0 = (bid & 127) << 6;
    const long rowbase = (long)b * T_LEN;
    const int klane = (lane >> 4) * 8;
    const int mrow = lane & 15;
    const int trow = (lane >> 4) * 4;
    const int tq_t = tid >> 2;     // owned row
    const int tq_q = tid & 3;      // owned 16-ch chunk

    // ---------------- prologue ----------------
    for (int idx = tid; idx < 768; idx += 256) {               // ctile (persistent)
        int row = idx / 12, seg = idx % 12;
        ix4 v = *(const ix4*)(cbf + (rowbase + t0 + row) * 96 + seg * 8);
        *(ix4*)(ctile + row * 104 + seg * 8) = v;
    }
    if (tid < 64)                                              // mask in ctile pad
        *(float*)(ctile + tid * 104 + 96) = xmask[rowbase + t0 + tid];
    float xc[16];
    {
        float xs = xin[rowbase + t0 + tq_t];
#pragma unroll
        for (int k = 0; k < 16; k++)
            xc[k] = fmaf(fw[tq_q * 16 + k], xs, fb[tq_q * 16 + k]);
    }
    fx4 racc[4][2];   // waves 2-3: skip fragments (f32)
#pragma unroll
    for (int m = 0; m < 4; m++) {
        racc[m][0] = (fx4){0.f, 0.f, 0.f, 0.f};
        racc[m][1] = (fx4){0.f, 0.f, 0.f, 0.f};
    }
    {   // publish x_0 snapshot (bf16, sc1)
        unsigned short* dst = xbfA + ((rowbase + t0 + tq_t) << 6) + tq_q * 16;
#pragma unroll
        for (int k2 = 0; k2 < 4; k2++)
            astore(dst + k2 * 4, pack4(xc[k2 * 4], xc[k2 * 4 + 1],
                                       xc[k2 * 4 + 2], xc[k2 * 4 + 3]));
    }
    gbar(bar, bid, 64u);

    // ---------------- layer loop ----------------
#pragma unroll 1
    for (int l = 0; l < LAYERS; l++) {
        const unsigned short* cur = (l & 1) ? xbfB : xbfA;
        unsigned short*       nxt = (l & 1) ? xbfA : xbfB;
        const int d = 1 << (l % 10);
        const unsigned short* wl = wpack + (size_t)l * 45056;

        // stage halo taps (sc1 loads) + center from registers
#pragma unroll
        for (int u = 0; u < 2; u++) {
            int idx = tid + u * 256;          // 512 units: 2 taps x 64 rows x 4 chunks
            int tp = idx >> 8;                // 0: -d, 1: +d
            int rem = idx & 255;
            int row = rem >> 2, qq = rem & 3;
            int tg = t0 + row + (tp ? d : -d);
            u64 a0 = 0, a1 = 0, a2 = 0, a3 = 0;
            if ((unsigned)tg < (unsigned)T_LEN) {
                const unsigned short* sp = cur + ((rowbase + tg) << 6) + qq * 16;
                a0 = aload(sp); a1 = aload(sp + 4); a2 = aload(sp + 8); a3 = aload(sp + 12);
            }
            u64* dl = (u64*)(xtap + (tp * 128 + row) * 72 + qq * 16);
            dl[0] = a0; dl[1] = a1; dl[2] = a2; dl[3] = a3;
        }
        {
            u64* dc = (u64*)(xtap + (64 + tq_t) * 72 + tq_q * 16);
#pragma unroll
            for (int k2 = 0; k2 < 4; k2++)
                dc[k2] = pack4(xc[k2 * 4], xc[k2 * 4 + 1], xc[k2 * 4 + 2], xc[k2 * 4 + 3]);
        }
        // H-GEMM B-fragment prefetch (plain cached; L2-hot)
        bfx8 bq[2][2];
#pragma unroll
        for (int pk = 0; pk < 2; pk++)
#pragma unroll
            for (int n = 0; n < 2; n++)
                bq[pk][n] = *(const bfx8*)(wl + (size_t)((pk * 8 + wv * 2 + n) * 64 + lane) * 8);
        __syncthreads();                                       // (1) taps ready

        // H GEMM: K = 3*64 conv taps + 96 aux(padded)
        fx4 acc[4][2];
#pragma unroll
        for (int m = 0; m < 4; m++) {
            acc[m][0] = (fx4){0.f, 0.f, 0.f, 0.f};
            acc[m][1] = (fx4){0.f, 0.f, 0.f, 0.f};
        }
#pragma unroll
        for (int ks = 0; ks < 9; ks++) {
            const unsigned short* abase; int off, stride;
            if (ks < 6) { abase = xtap + (ks >> 1) * (64 * 72); off = (ks & 1) * 32; stride = 72; }
            else        { abase = ctile;                        off = (ks - 6) * 32; stride = 104; }
            bfx8 af[4];
#pragma unroll
            for (int m = 0; m < 4; m++)
                af[m] = *(const bfx8*)(abase + (m * 16 + mrow) * stride + off + klane);
            bfx8 b0 = bq[ks & 1][0], b1 = bq[ks & 1][1];
            if (ks + 2 < 9) {
#pragma unroll
                for (int n = 0; n < 2; n++)
                    bq[ks & 1][n] = *(const bfx8*)(wl + (size_t)(((ks + 2) * 8 + wv * 2 + n) * 64 + lane) * 8);
            }
#pragma unroll
            for (int m = 0; m < 4; m++) {
                acc[m][0] = __builtin_amdgcn_mfma_f32_16x16x32_bf16(af[m], b0, acc[m][0], 0, 0, 0);
                acc[m][1] = __builtin_amdgcn_mfma_f32_16x16x32_bf16(af[m], b1, acc[m][1], 0, 0, 0);
            }
        }
        __syncthreads();                                       // (2) xtap dead

        // split gate
        {
            float cb0 = conv_b[l * 128 + wv * 32 + mrow];
            float cb1 = conv_b[l * 128 + wv * 32 + 16 + mrow];
            if (wv >= 2) {        // sigma(xb) -> sg_l (ch 64..127)
#pragma unroll
                for (int n = 0; n < 2; n++) {
                    int col = (wv - 2) * 32 + n * 16 + mrow;
                    float cb = n ? cb1 : cb0;
#pragma unroll
                    for (int m = 0; m < 4; m++)
#pragma unroll
                        for (int r = 0; r < 4; r++) {
                            float h = acc[m][n][r] + cb;
                            sg_l[(m * 16 + trow + r) * 68 + col] = 1.f / (1.f + __expf(-h));
                        }
                }
            } else {              // tanh(xa) in-register (ch 0..63)
#pragma unroll
                for (int n = 0; n < 2; n++) {
                    float cb = n ? cb1 : cb0;
#pragma unroll
                    for (int m = 0; m < 4; m++)
#pragma unroll
                        for (int r = 0; r < 4; r++) {
                            float h = acc[m][n][r] + cb;
                            float e2 = __expf(2.f * h);
                            acc[m][n][r] = 1.f - 2.f / (e2 + 1.f);
                        }
                }
            }
        }
        __syncthreads();                                       // (3) sg ready

        // O-GEMM B prefetch (overlaps z-compute)
        bfx8 ob[2][2];
#pragma unroll
        for (int ks = 0; ks < 2; ks++)
#pragma unroll
            for (int n = 0; n < 2; n++)
                ob[ks][n] = *(const bfx8*)(wl + (size_t)(((72 + ks * 8) + (wv * 2 + n)) * 64 + lane) * 8);

        if (wv < 2) {             // z = tanh * sigma -> z_l bf16
#pragma unroll
            for (int n = 0; n < 2; n++) {
                int col = wv * 32 + n * 16 + mrow;
#pragma unroll
                for (int m = 0; m < 4; m++)
#pragma unroll
                    for (int r = 0; r < 4; r++) {
                        int t = m * 16 + trow + r;
                        z_l[t * 72 + col] = f2bf(acc[m][n][r] * sg_l[t * 68 + col]);
                    }
            }
        }
        __syncthreads();                                       // (4) z ready

        // O GEMM: K = 64
        fx4 acc2[4][2];
#pragma unroll
        for (int m = 0; m < 4; m++) {
            acc2[m][0] = (fx4){0.f, 0.f, 0.f, 0.f};
            acc2[m][1] = (fx4){0.f, 0.f, 0.f, 0.f};
        }
#pragma unroll
        for (int ks = 0; ks < 2; ks++) {
            bfx8 af[4];
#pragma unroll
            for (int m = 0; m < 4; m++)
                af[m] = *(const bfx8*)(z_l + (m * 16 + mrow) * 72 + ks * 32 + klane);
#pragma unroll
            for (int m = 0; m < 4; m++) {
                acc2[m][0] = __builtin_amdgcn_mfma_f32_16x16x32_bf16(af[m], ob[ks][0], acc2[m][0], 0, 0, 0);
                acc2[m][1] = __builtin_amdgcn_mfma_f32_16x16x32_bf16(af[m], ob[ks][1], acc2[m][1], 0, 0, 0);
            }
        }
        __syncthreads();                                       // (5) z consumed; o_l may overlay

        // epilogue: waves 0-1 -> o_l (x half, p<64, stride 68: SAFE);
        //           waves 2-3 -> skip fragments directly (mask from ctile pad)
        if (wv < 2) {
#pragma unroll
            for (int n = 0; n < 2; n++) {
                int p = wv * 32 + n * 16 + mrow;               // 0..63
                float ob_ = out_b[l * 128 + p];
#pragma unroll
                for (int m = 0; m < 4; m++)
#pragma unroll
                    for (int r = 0; r < 4; r++)
                        o_l[(m * 16 + trow + r) * 68 + p] = acc2[m][n][r] + ob_;
            }
        } else {
#pragma unroll
            for (int n = 0; n < 2; n++) {
                int p = wv * 32 + n * 16 + mrow;               // 64..127
                float ob_ = out_b[l * 128 + p];
#pragma unroll
                for (int m = 0; m < 4; m++)
#pragma unroll
                    for (int r = 0; r < 4; r++) {
                        int t = m * 16 + trow + r;
                        float mk2 = *(const float*)(ctile + t * 104 + 96);
                        racc[m][n][r] = fmaf(acc2[m][n][r] + ob_, mk2, racc[m][n][r]);
                    }
            }
        }
        __syncthreads();                                       // (6) o ready

        // drain: xc update from o_l + publish next snapshot
        {
            float mkr = *(const float*)(ctile + tq_t * 104 + 96);
            const float* osrc = o_l + tq_t * 68 + tq_q * 16;
#pragma unroll
            for (int k = 0; k < 16; k++)
                xc[k] = fmaf(osrc[k], mkr, xc[k]);
            if (l < LAYERS - 1) {
                unsigned short* dst = nxt + ((rowbase + t0 + tq_t) << 6) + tq_q * 16;
#pragma unroll
                for (int k2 = 0; k2 < 4; k2++)
                    astore(dst + k2 * 4, pack4(xc[k2 * 4], xc[k2 * 4 + 1],
                                               xc[k2 * 4 + 2], xc[k2 * 4 + 3]));
            }
        }
        if (l < LAYERS - 1)
            gbar(bar, bid, 64u * (unsigned)(l + 2));
    }

    // ---------------- fused last_conv ----------------
    __syncthreads();                       // o_l dead; ctile dead; overlay
    float* s_lds = (float*)smem;           // [64][68] f32 (raw skip)
    float* w1s   = (float*)(smem + 17408); // [j][o] transposed, 16 KB
    float* b1s   = (float*)(smem + 33792);
    float* w2s   = (float*)(smem + 34048);
    if (wv >= 2) {
#pragma unroll
        for (int n = 0; n < 2; n++) {
            int col = (wv - 2) * 32 + n * 16 + mrow;
#pragma unroll
            for (int m = 0; m < 4; m++)
#pragma unroll
                for (int r = 0; r < 4; r++)
                    s_lds[(m * 16 + trow + r) * 68 + col] = racc[m][n][r];
        }
    }
    for (int i = tid; i < 4096; i += 256)
        w1s[(i & 63) * 64 + (i >> 6)] = lw1[i];     // w1s[j][o] = lw1[o][j]
    if (tid < 64) { b1s[tid] = lb1[tid]; w2s[tid] = lw2[tid]; }
    __syncthreads();
    {
        float accf[16];
#pragma unroll
        for (int oi = 0; oi < 16; oi++) accf[oi] = b1s[tq_q * 16 + oi];
        for (int j = 0; j < 64; j++) {
            float s = fmaxf(s_lds[tq_t * 68 + j], 0.f);
            const float* wr = w1s + j * 64 + tq_q * 16;
#pragma unroll
            for (int oi = 0; oi < 16; oi++) accf[oi] = fmaf(wr[oi], s, accf[oi]);
        }
        float tot = 0.f;
#pragma unroll
        for (int oi = 0; oi < 16; oi++)
            tot = fmaf(w2s[tq_q * 16 + oi], fmaxf(accf[oi], 0.f), tot);
        tot += __shfl_xor(tot, 1);
        tot += __shfl_xor(tot, 2);
        if (tq_q == 0) out[rowbase + t0 + tq_t] = tot + lb2[0];
    }
}

extern "C" void kernel_launch(void* const* d_in, const int* in_sizes, int n_in,
                              void* d_out, int out_size, void* d_ws, size_t ws_size,
                              hipStream_t stream) {
    const float* x       = (const float*)d_in[0];
    const float* xmask   = (const float*)d_in[1];
    const float* c       = (const float*)d_in[2];
    const float* first_w = (const float*)d_in[3];
    const float* first_b = (const float*)d_in[4];
    const float* conv_w  = (const float*)d_in[5];
    const float* conv_b  = (const float*)d_in[6];
    const float* aux_w   = (const float*)d_in[7];
    const float* out_w   = (const float*)d_in[8];
    const float* out_b   = (const float*)d_in[9];
    const float* lw1     = (const float*)d_in[10];
    const float* lb1     = (const float*)d_in[11];
    const float* lw2     = (const float*)d_in[12];
    const float* lb2     = (const float*)d_in[13];
    float* outp = (float*)d_out;

    char* ws = (char*)d_ws;
    unsigned short* xbfA  = (unsigned short*)(ws + 0);          //  8,388,608 B
    unsigned short* xbfB  = (unsigned short*)(ws + 8388608);    //  8,388,608 B
    unsigned short* cbf   = (unsigned short*)(ws + 16777216);   // 12,582,912 B
    unsigned short* wpack = (unsigned short*)(ws + 29360128);   //  2,703,360 B
    unsigned*       bar   = (unsigned*)(ws + 32063488);         //  8,192 B

    pack_weights_k<<<660, 256, 0, stream>>>(conv_w, aux_w, out_w, wpack, bar);
    prep_c_k<<<1024, 256, 0, stream>>>(c, cbf);
    // Plain launch only: 1024 blocks = exactly 4/CU x 256 CU co-resident by
    // capacity (LDS 40960 -> 4/CU; launch_bounds caps VGPR at 128).
    mega_k<<<1024, 256, 0, stream>>>(x, xmask, cbf, first_w, first_b,
                                     conv_b, out_b, lw1, lb1, lw2, lb2,
                                     xbfA, xbfB, wpack, bar, outp);
}